// Round 1
// 1382.859 us; speedup vs baseline: 1.0291x; 1.0291x over previous
//
#include <hip/hip_runtime.h>

namespace {
constexpr int kB = 4, kH = 16, kS = 2048, kD = 64;
constexpr int ROWS = 64;          // query rows per block
constexpr int KT = 64;            // keys per tile
constexpr int NT = kS / KT;       // 32 key tiles
constexpr float SCALE = 0.125f;   // 1/sqrt(64)
constexpr long long CTXN = (long long)kB * kH * kS * kD;
constexpr size_t TENS = (size_t)kB * kH * kS * kD;        // 8388608 elems
constexpr size_t WS_NEED = TENS * sizeof(short) * 3;      // Qb+Kb+Vtb = 50.3MB
}

typedef __attribute__((ext_vector_type(4))) float f32x4;
typedef __attribute__((ext_vector_type(8))) short bf16x8;

__device__ __forceinline__ short f2bf(float f) {
  union { float f; unsigned u; } x; x.f = f;
  return (short)((x.u + 0x7fffu + ((x.u >> 16) & 1u)) >> 16);  // RNE
}

__device__ __forceinline__ f32x4 mfma16(bf16x8 a, bf16x8 b, f32x4 c) {
  return __builtin_amdgcn_mfma_f32_16x16x32_bf16(a, b, c, 0, 0, 0);
}

// async global->LDS, 16B per lane; LDS dest = wave-uniform base + lane*16
__device__ __forceinline__ void gload16(const void* g, void* l) {
  __builtin_amdgcn_global_load_lds(
      (const __attribute__((address_space(1))) unsigned*)g,
      (__attribute__((address_space(3))) unsigned*)l, 16, 0, 0);
}

// read one 16B fragment from a [64][64]-short tile with chunk-XOR swizzle.
// logical chunk in 0..7; physical chunk = chunk ^ (row&7).
__device__ __forceinline__ bf16x8 frag_ld(const short* base, int row, int chunk) {
  return *(const bf16x8*)(base + row * 64 + ((chunk ^ (row & 7)) << 3));
}

// stage a contiguous 64x64-short tile (8KB): 2 DMA calls per thread
__device__ __forceinline__ void stage_rows(short* dst, const short* src,
                                           int wave, int lane) {
  gload16(src + wave * 1024 + lane * 8, dst + wave * 1024);
  gload16(src + wave * 1024 + 512 + lane * 8, dst + wave * 1024 + 512);
}

// stage V^T tile t: LDS row d <- Vtb[d][t*64 .. t*64+64); rows are kS apart
__device__ __forceinline__ void stage_vt(short* dst, const short* vg, int t,
                                         int wave, int lane) {
  const int d0 = wave * 16 + (lane >> 3);
  gload16(vg + (size_t)d0 * kS + t * 64 + (lane & 7) * 8, dst + wave * 1024);
  gload16(vg + (size_t)(d0 + 8) * kS + t * 64 + (lane & 7) * 8,
          dst + wave * 1024 + 512);
}

// ---------------- pre-pass: fp32 -> bf16 with chunk swizzle ----------------
// Q/K: out[row][ (c ^ (row&7))*8 + e ] = in[row][c*8+e]
__global__ __launch_bounds__(256)
void convert_qk(const float* __restrict__ q, const float* __restrict__ k,
                short* __restrict__ qb, short* __restrict__ kb) {
  const unsigned idx = blockIdx.x * 256 + threadIdx.x;   // 2*2^20 threads
  const unsigned i = idx & 0xFFFFFu;                     // 2^20 chunks/tensor
  const bool isk = (idx >> 20) != 0;
  const unsigned row = i >> 3, c = i & 7;
  const float* src = (isk ? k : q) + ((size_t)row << 6) + (c << 3);
  short* dst = (isk ? kb : qb) + ((size_t)row << 6) + ((c ^ (row & 7u)) << 3);
  const float4 f0 = ((const float4*)src)[0];
  const float4 f1 = ((const float4*)src)[1];
  bf16x8 h;
  h[0] = f2bf(f0.x); h[1] = f2bf(f0.y); h[2] = f2bf(f0.z); h[3] = f2bf(f0.w);
  h[4] = f2bf(f1.x); h[5] = f2bf(f1.y); h[6] = f2bf(f1.z); h[7] = f2bf(f1.w);
  *(bf16x8*)dst = h;
}

// V -> V^T [bh][d][s], swizzled within each 64-key group by (d&7)
__global__ __launch_bounds__(256)
void convert_vt(const float* __restrict__ v, short* __restrict__ vtb) {
  const int gw = blockIdx.x * 4 + (threadIdx.x >> 6);  // one (bh, s-octet)/wave
  const int d = threadIdx.x & 63;
  const int bh = gw >> 8;
  const int so = (gw & 255) << 3;                      // octet start in S
  const float* src = v + ((size_t)bh * kS + so) * kD + d;
  bf16x8 h;
#pragma unroll
  for (int i = 0; i < 8; ++i) h[i] = f2bf(src[(size_t)i * kD]);
  short* dst = vtb + (size_t)bh * kS * kD + (size_t)d * kS + (so & ~63)
             + ((((so >> 3) & 7) ^ (d & 7)) << 3);
  *(bf16x8*)dst = h;
}

// ---------------- main kernel: bf16 inputs, async staging ----------------
__global__ __launch_bounds__(256, 3)
void attn_fast(const short* __restrict__ qb, const short* __restrict__ kb,
               const short* __restrict__ vtb, const float* __restrict__ mask,
               float* __restrict__ outctx, float* __restrict__ outatt) {
  __shared__ short q_s[64 * 64];      // 8KB, swizzled linear
  __shared__ short k_s[64 * 64];      // 8KB
  __shared__ short v_s[2][64 * 64];   // 16KB (V^T double buffer; K ping in p1)
  __shared__ short p_s[4][16][72];    // per-wave P tile (pad-72 layout)
  __shared__ float mask_s[kS];        // 8KB

  const int tid = threadIdx.x;
  const int lane = tid & 63;
  const int wave = tid >> 6;
  const int quad = lane >> 4;
  const int l16 = lane & 15;

  const int bh = blockIdx.x >> 5;   // qt fast-varying: same-bh blocks adjacent
  const int qt = blockIdx.x & 31;
  const int qbase = qt * ROWS;
  const int bb = bh >> 4;

  const short* qgp = qb + ((size_t)bh * kS + qbase) * kD;
  const short* kgp = kb + (size_t)bh * kS * kD;
  const short* vgp = vtb + (size_t)bh * kS * kD;
  const float* mg = mask + (size_t)bb * kS;

  for (int i = tid; i < kS / 4; i += 256)
    ((float4*)mask_s)[i] = ((const float4*)mg)[i];

  stage_rows(q_s, qgp, wave, lane);                 // Q tile once
  stage_rows(k_s, kgp, wave, lane);                 // K[0]
  __syncthreads();                                  // full drain

  const int arow = wave * 16 + l16;
  const bf16x8 a0 = frag_ld(q_s, arow, quad);
  const bf16x8 a1 = frag_ld(q_s, arow, 4 + quad);

  // ---------------- Pass 1: row sums of exp(s) (m=0 safe: |s| <~ 6) ----
  float rs[4] = {0.f, 0.f, 0.f, 0.f};
#pragma unroll 1
  for (int t = 0; t < NT; ++t) {
    const short* cur = (t & 1) ? v_s[0] : k_s;
    if (t + 1 < NT)   // prefetch K[t+1] into the buffer freed last iter
      stage_rows((t & 1) ? k_s : v_s[0], kgp + ((size_t)(t + 1) << 12), wave, lane);
#pragma unroll
    for (int ct = 0; ct < 4; ++ct) {
      const int row = ct * 16 + l16;
      const bf16x8 b0 = frag_ld(cur, row, quad);
      const bf16x8 b1 = frag_ld(cur, row, 4 + quad);
      f32x4 acc = {0.f, 0.f, 0.f, 0.f};
      acc = mfma16(a0, b0, acc);
      acc = mfma16(a1, b1, acc);
      const float mk = mask_s[t * KT + ct * 16 + l16];
#pragma unroll
      for (int r = 0; r < 4; ++r)
        rs[r] += __expf(acc[r] * SCALE + mk);   // row = quad*4+r, col = l16
    }
    __syncthreads();   // drains K[t+1] (covered by this tile's compute)
  }

  float rcl[4];
#pragma unroll
  for (int r = 0; r < 4; ++r) {
    float s = rs[r];
    s += __shfl_xor(s, 1);
    s += __shfl_xor(s, 2);
    s += __shfl_xor(s, 4);
    s += __shfl_xor(s, 8);
    rcl[r] = 1.0f / s;
  }

  // ---------------- Pass 2: recompute, write attention, accumulate PV ----
  f32x4 o[4];
#pragma unroll
  for (int dt = 0; dt < 4; ++dt) o[dt] = (f32x4){0.f, 0.f, 0.f, 0.f};

  float* attw = outatt + ((size_t)bh * kS + qbase + wave * 16 + quad * 4) * kS;

  stage_rows(k_s, kgp, wave, lane);       // K[0]
  stage_vt(v_s[0], vgp, 0, wave, lane);   // V[0]
  __syncthreads();                        // full drain (once)

  // steady-state VMEM window invariants (per thread, in order):
  //  entry of iter t: outstanding = V[t] (2 loads)
  //  phaseA issues exactly 16 att stores
  //  B1: vmcnt(16) -> waits the 2 oldest = V[t]; stores keep draining
  //  post-B1: K[t+1] (2), V[t+1] (2)
  //  B2: vmcnt(2)  -> waits stores + K[t+1]; leaves V[t+1] in flight
#pragma unroll 1
  for (int t = 0; t < NT; ++t) {
    // phase A: QK^T from k_s (bit-identical to pass 1), write att + p_s
#pragma unroll
    for (int ct = 0; ct < 4; ++ct) {
      const int row = ct * 16 + l16;
      const bf16x8 b0 = frag_ld(k_s, row, quad);
      const bf16x8 b1 = frag_ld(k_s, row, 4 + quad);
      f32x4 acc = {0.f, 0.f, 0.f, 0.f};
      acc = mfma16(a0, b0, acc);
      acc = mfma16(a1, b1, acc);
      const float mk = mask_s[t * KT + ct * 16 + l16];
      const int col = t * KT + ct * 16 + l16;
#pragma unroll
      for (int r = 0; r < 4; ++r) {
        const float p = __expf(acc[r] * SCALE + mk) * rcl[r];
        attw[(size_t)r * kS + col] = p;                    // fp32 attention out
        p_s[wave][quad * 4 + r][ct * 16 + l16] = f2bf(p);  // C-layout -> LDS
      }
    }
    // p_s is wave-private; DS pipe is in-order per wave
    __builtin_amdgcn_wave_barrier();
    const bf16x8 pa0 = *(const bf16x8*)&p_s[wave][l16][quad * 8];
    const bf16x8 pa1 = *(const bf16x8*)&p_s[wave][l16][32 + quad * 8];

    // B1: V[t] landed (2 oldest of {V[t], 16 stores}); don't drain stores
    asm volatile("s_waitcnt vmcnt(16)" ::: "memory");
    __builtin_amdgcn_s_barrier();
    asm volatile("" ::: "memory");

    if (t + 1 < NT) {
      stage_rows(k_s, kgp + ((size_t)(t + 1) << 12), wave, lane);  // K[t+1]
      stage_vt(v_s[(t + 1) & 1], vgp, t + 1, wave, lane);          // V[t+1]
    }

    // phase B: PV from V^T[t]
    const short* vt = v_s[t & 1];
    __builtin_amdgcn_s_setprio(1);
#pragma unroll
    for (int dt = 0; dt < 4; ++dt) {
      const int row = dt * 16 + l16;
      const bf16x8 w0 = frag_ld(vt, row, quad);
      const bf16x8 w1 = frag_ld(vt, row, 4 + quad);
      o[dt] = mfma16(pa0, w0, o[dt]);
      o[dt] = mfma16(pa1, w1, o[dt]);
    }
    __builtin_amdgcn_s_setprio(0);

    // B2: K[t+1] landed; leave V[t+1] (the 2 newest) in flight
    asm volatile("s_waitcnt vmcnt(2)" ::: "memory");
    __builtin_amdgcn_s_barrier();
    asm volatile("" ::: "memory");
  }

  float* cw = outctx + ((size_t)bh * kS + qbase + wave * 16 + quad * 4) * kD;
#pragma unroll
  for (int dt = 0; dt < 4; ++dt)
#pragma unroll
    for (int r = 0; r < 4; ++r)
      cw[(size_t)r * kD + dt * 16 + l16] = o[dt][r];
}

// ---------------- fallback (previous harness-verified kernel) ----------------
__device__ __forceinline__ void cvt_row16(short* dst, const float4* src) {
  float4 f0 = src[0], f1 = src[1], f2 = src[2], f3 = src[3];
  bf16x8 h0, h1;
  h0[0] = f2bf(f0.x); h0[1] = f2bf(f0.y); h0[2] = f2bf(f0.z); h0[3] = f2bf(f0.w);
  h0[4] = f2bf(f1.x); h0[5] = f2bf(f1.y); h0[6] = f2bf(f1.z); h0[7] = f2bf(f1.w);
  h1[0] = f2bf(f2.x); h1[1] = f2bf(f2.y); h1[2] = f2bf(f2.z); h1[3] = f2bf(f2.w);
  h1[4] = f2bf(f3.x); h1[5] = f2bf(f3.y); h1[6] = f2bf(f3.z); h1[7] = f2bf(f3.w);
  *(bf16x8*)(dst) = h0;
  *(bf16x8*)(dst + 8) = h1;
}

__global__ __launch_bounds__(256, 3)
void attn_fwd(const float* __restrict__ q, const float* __restrict__ kk,
              const float* __restrict__ vv, const float* __restrict__ mask,
              float* __restrict__ outctx, float* __restrict__ outatt) {
  __shared__ short q_s[ROWS][72];
  __shared__ short k_s[KT][72];
  __shared__ short vt_s[kD][72];
  __shared__ short p_s[4][16][72];
  __shared__ float mask_s[kS];

  const int tid = threadIdx.x;
  const int lane = tid & 63;
  const int wave = tid >> 6;
  const int quad = lane >> 4;
  const int l16 = lane & 15;

  const int bh = blockIdx.x >> 5;
  const int qt = blockIdx.x & 31;
  const int qbase = qt * ROWS;
  const int bb = bh >> 4;

  const float* qg = q + ((size_t)bh * kS + qbase) * kD;
  const float* kg = kk + (size_t)bh * kS * kD;
  const float* vg = vv + (size_t)bh * kS * kD;
  const float* mg = mask + (size_t)bb * kS;

  for (int i = tid; i < kS / 4; i += 256)
    ((float4*)mask_s)[i] = ((const float4*)mg)[i];

  {
    const int row = tid >> 2, c0 = (tid & 3) << 4;
    cvt_row16(&q_s[row][c0], (const float4*)(qg + row * kD + c0));
  }
  __syncthreads();

  const bf16x8 a0 = *(const bf16x8*)&q_s[wave * 16 + l16][quad * 8];
  const bf16x8 a1 = *(const bf16x8*)&q_s[wave * 16 + l16][32 + quad * 8];

  float rs[4] = {0.f, 0.f, 0.f, 0.f};
  for (int t = 0; t < NT; ++t) {
    __syncthreads();
    {
      const int row = tid >> 2, c0 = (tid & 3) << 4;
      cvt_row16(&k_s[row][c0],
                (const float4*)(kg + ((size_t)(t * KT + row)) * kD + c0));
    }
    __syncthreads();
#pragma unroll
    for (int ct = 0; ct < 4; ++ct) {
      const bf16x8 b0 = *(const bf16x8*)&k_s[ct * 16 + l16][quad * 8];
      const bf16x8 b1 = *(const bf16x8*)&k_s[ct * 16 + l16][32 + quad * 8];
      f32x4 acc = {0.f, 0.f, 0.f, 0.f};
      acc = mfma16(a0, b0, acc);
      acc = mfma16(a1, b1, acc);
      const float mk = mask_s[t * KT + ct * 16 + l16];
#pragma unroll
      for (int r = 0; r < 4; ++r)
        rs[r] += __expf(acc[r] * SCALE + mk);
    }
  }

  float rcl[4];
#pragma unroll
  for (int r = 0; r < 4; ++r) {
    float s = rs[r];
    s += __shfl_xor(s, 1);
    s += __shfl_xor(s, 2);
    s += __shfl_xor(s, 4);
    s += __shfl_xor(s, 8);
    rcl[r] = 1.0f / s;
  }

  f32x4 o[4];
#pragma unroll
  for (int dt = 0; dt < 4; ++dt) o[dt] = (f32x4){0.f, 0.f, 0.f, 0.f};

  float* attw = outatt + ((size_t)bh * kS + qbase + wave * 16 + quad * 4) * kS;

  for (int t = 0; t < NT; ++t) {
    __syncthreads();
    {
      const int row = tid >> 2, c0 = (tid & 3) << 4;
      cvt_row16(&k_s[row][c0],
                (const float4*)(kg + ((size_t)(t * KT + row)) * kD + c0));
      const float4* vsrc = (const float4*)(vg + ((size_t)(t * KT + row)) * kD + c0);
      float4 g0 = vsrc[0], g1 = vsrc[1], g2 = vsrc[2], g3 = vsrc[3];
      vt_s[c0 + 0][row] = f2bf(g0.x);  vt_s[c0 + 1][row] = f2bf(g0.y);
      vt_s[c0 + 2][row] = f2bf(g0.z);  vt_s[c0 + 3][row] = f2bf(g0.w);
      vt_s[c0 + 4][row] = f2bf(g1.x);  vt_s[c0 + 5][row] = f2bf(g1.y);
      vt_s[c0 + 6][row] = f2bf(g1.z);  vt_s[c0 + 7][row] = f2bf(g1.w);
      vt_s[c0 + 8][row] = f2bf(g2.x);  vt_s[c0 + 9][row] = f2bf(g2.y);
      vt_s[c0 + 10][row] = f2bf(g2.z); vt_s[c0 + 11][row] = f2bf(g2.w);
      vt_s[c0 + 12][row] = f2bf(g3.x); vt_s[c0 + 13][row] = f2bf(g3.y);
      vt_s[c0 + 14][row] = f2bf(g3.z); vt_s[c0 + 15][row] = f2bf(g3.w);
    }
    __syncthreads();
#pragma unroll
    for (int ct = 0; ct < 4; ++ct) {
      const bf16x8 b0 = *(const bf16x8*)&k_s[ct * 16 + l16][quad * 8];
      const bf16x8 b1 = *(const bf16x8*)&k_s[ct * 16 + l16][32 + quad * 8];
      f32x4 acc = {0.f, 0.f, 0.f, 0.f};
      acc = mfma16(a0, b0, acc);
      acc = mfma16(a1, b1, acc);
      const float mk = mask_s[t * KT + ct * 16 + l16];
      const int col = t * KT + ct * 16 + l16;
#pragma unroll
      for (int r = 0; r < 4; ++r) {
        const float p = __expf(acc[r] * SCALE + mk) * rcl[r];
        attw[(size_t)r * kS + col] = p;
        p_s[wave][quad * 4 + r][ct * 16 + l16] = f2bf(p);
      }
    }
    __builtin_amdgcn_wave_barrier();
    const bf16x8 pa0 = *(const bf16x8*)&p_s[wave][l16][quad * 8];
    const bf16x8 pa1 = *(const bf16x8*)&p_s[wave][l16][32 + quad * 8];
#pragma unroll
    for (int dt = 0; dt < 4; ++dt) {
      const bf16x8 w0 = *(const bf16x8*)&vt_s[dt * 16 + l16][quad * 8];
      const bf16x8 w1 = *(const bf16x8*)&vt_s[dt * 16 + l16][32 + quad * 8];
      o[dt] = mfma16(pa0, w0, o[dt]);
      o[dt] = mfma16(pa1, w1, o[dt]);
    }
  }

  float* cw = outctx + ((size_t)bh * kS + qbase + wave * 16 + quad * 4) * kD;
#pragma unroll
  for (int dt = 0; dt < 4; ++dt)
#pragma unroll
    for (int r = 0; r < 4; ++r)
      cw[(size_t)r * kD + dt * 16 + l16] = o[dt][r];
}

extern "C" void kernel_launch(void* const* d_in, const int* in_sizes, int n_in,
                              void* d_out, int out_size, void* d_ws, size_t ws_size,
                              hipStream_t stream) {
  const float* q = (const float*)d_in[0];
  const float* k = (const float*)d_in[1];
  const float* v = (const float*)d_in[2];
  const float* mask = (const float*)d_in[3];
  float* ctx = (float*)d_out;
  float* att = (float*)d_out + CTXN;
  if (d_ws != nullptr && ws_size >= WS_NEED) {
    short* qb = (short*)d_ws;
    short* kb = qb + TENS;
    short* vtb = kb + TENS;
    convert_qk<<<dim3(8192), dim3(256), 0, stream>>>(q, k, qb, kb);
    convert_vt<<<dim3(4096), dim3(256), 0, stream>>>(v, vtb);
    attn_fast<<<dim3(kB * kH * NT), dim3(256), 0, stream>>>(qb, kb, vtb, mask,
                                                            ctx, att);
  } else {
    attn_fwd<<<dim3(kB * kH * NT), dim3(256), 0, stream>>>(q, k, v, mask, ctx,
                                                           att);
  }
}